// Round 1
// baseline (114.909 us; speedup 1.0000x reference)
//
#include <hip/hip_runtime.h>

#define DIM 32
#define KK 64
#define NHOP 2
#define WAVES_PER_BLOCK 4

__device__ __forceinline__ float rcp_fast(float x) { return __builtin_amdgcn_rcpf(x); }

// tanh(x) = 1 - 2/(exp(2x)+1); graceful at +-inf (rcp(inf)=0)
__device__ __forceinline__ float tanh_fast(float x) {
    float t = __expf(2.0f * x);
    return 1.0f - 2.0f * rcp_fast(t + 1.0f);
}

__global__ __launch_bounds__(256) void ripple_fwd(
    const int* __restrict__ users,
    const int* __restrict__ items,
    const int* __restrict__ hop0_items,
    const int* __restrict__ heads,
    const int* __restrict__ relations,
    const int* __restrict__ tails,
    const float* __restrict__ entity_emb,
    const float* __restrict__ relation_emb,
    const float* __restrict__ rec_user_emb,
    const float* __restrict__ rec_item_emb,
    const float* __restrict__ W_ih,
    const float* __restrict__ W_hh,
    const float* __restrict__ b_ih,
    const float* __restrict__ b_hh,
    float* __restrict__ out,
    const int B)
{
    // per-lane scratch for h2 pre-activation tr-part; stride 33 -> conflict-free
    __shared__ float trbuf[WAVES_PER_BLOCK][KK][DIM + 1];
    const int wave = threadIdx.x >> 6;
    const int lane = threadIdx.x & 63;
    const int b = __builtin_amdgcn_readfirstlane(blockIdx.x * WAVES_PER_BLOCK + wave);
    if (b >= B) return;  // wave-uniform

    // q = entity_emb[item] + rec_item_emb[item]  (wave-uniform -> s_load)
    const int it = __builtin_amdgcn_readfirstlane(items[b]);
    const int uu = __builtin_amdgcn_readfirstlane(users[b]);

    float q[DIM];
    #pragma unroll
    for (int d = 0; d < DIM; ++d)
        q[d] = entity_emb[(size_t)it * DIM + d] + rec_item_emb[(size_t)it * DIM + d];

    // rec_user . q  (uniform on all lanes)
    float total = 0.0f;
    #pragma unroll
    for (int d = 0; d < DIM; ++d)
        total = fmaf(rec_user_emb[(size_t)uu * DIM + d], q[d], total);

    // hop-0: sum_k entity[hop0[b,k]] . q
    {
        const int idx = hop0_items[b * KK + lane];
        const float4* rp = reinterpret_cast<const float4*>(entity_emb + (size_t)idx * DIM);
        float part = 0.0f;
        #pragma unroll
        for (int i = 0; i < DIM / 4; ++i) {
            float4 v = rp[i];
            part = fmaf(v.x, q[4 * i + 0], part);
            part = fmaf(v.y, q[4 * i + 1], part);
            part = fmaf(v.z, q[4 * i + 2], part);
            part = fmaf(v.w, q[4 * i + 3], part);
        }
        #pragma unroll
        for (int m = 32; m >= 1; m >>= 1) part += __shfl_xor(part, m, 64);
        total += part;
    }

    float* tr_lds = &trbuf[wave][lane][0];

    for (int l = 0; l < NHOP; ++l) {
        const int base = (l * B + b) * KK + lane;
        const int ih  = heads[base];
        const int ir  = relations[base];
        const int itl = tails[base];

        float h[DIM], r[DIM], t[DIM];
        {
            const float4* hp = reinterpret_cast<const float4*>(entity_emb + (size_t)ih * DIM);
            const float4* tp = reinterpret_cast<const float4*>(entity_emb + (size_t)itl * DIM);
            const float4* rp = reinterpret_cast<const float4*>(relation_emb + (size_t)ir * DIM);
            #pragma unroll
            for (int i = 0; i < DIM / 4; ++i) {
                float4 v = hp[i];
                h[4 * i] = v.x; h[4 * i + 1] = v.y; h[4 * i + 2] = v.z; h[4 * i + 3] = v.w;
            }
            #pragma unroll
            for (int i = 0; i < DIM / 4; ++i) {
                float4 v = tp[i];
                t[4 * i] = v.x; t[4 * i + 1] = v.y; t[4 * i + 2] = v.z; t[4 * i + 3] = v.w;
            }
            #pragma unroll
            for (int i = 0; i < DIM / 4; ++i) {
                float4 v = rp[i];
                r[4 * i] = v.x; r[4 * i + 1] = v.y; r[4 * i + 2] = v.z; r[4 * i + 3] = v.w;
            }
        }

        // score = h.t + r.r   (= (hr*tr).sum(-1))
        float score = 0.0f;
        #pragma unroll
        for (int e = 0; e < DIM; ++e) {
            score = fmaf(h[e], t[e], score);
            score = fmaf(r[e], r[e], score);
        }

        float h2acc[DIM];
        #pragma unroll
        for (int e = 0; e < DIM; ++e) h2acc[e] = 0.0f;

        // RNN step 1 (rolled over d; weights via wave-uniform s_load)
        #pragma unroll 1
        for (int d = 0; d < DIM; ++d) {
            const float* wrow = W_ih + d * (2 * DIM);
            float sh = 0.0f, st = 0.0f, sr = 0.0f;
            #pragma unroll
            for (int e = 0; e < DIM; ++e) {
                const float w0 = wrow[e];
                const float w1 = wrow[DIM + e];
                sh = fmaf(w0, h[e], sh);
                st = fmaf(w0, t[e], st);
                sr = fmaf(w1, r[e], sr);   // shared between hr and tr paths
            }
            const float bias = b_ih[d] + b_hh[d];
            const float h1d = tanh_fast(sh + sr + bias);
            tr_lds[d] = st + sr + bias;                 // h2 pre-act, tr part
            #pragma unroll
            for (int e = 0; e < DIM; ++e)               // h2 pre-act, W_hh part
                h2acc[e] = fmaf(W_hh[e * DIM + d], h1d, h2acc[e]);
        }

        // RNN step 2 + dot with q (h2 never materialized beyond scalar)
        float sk = 0.0f;
        #pragma unroll
        for (int e = 0; e < DIM; ++e) {
            const float h2e = tanh_fast(h2acc[e] + tr_lds[e]);
            sk = fmaf(h2e, q[e], sk);
        }

        // one-pass softmax-weighted accumulation (scores bounded ~|2|)
        const float ex = __expf(score);
        float num = ex * sk;
        float den = ex;
        #pragma unroll
        for (int m = 32; m >= 1; m >>= 1) {
            num += __shfl_xor(num, m, 64);
            den += __shfl_xor(den, m, 64);
        }
        total += num * rcp_fast(den);
    }

    if (lane == 0) {
        out[b] = rcp_fast(1.0f + __expf(-total));
    }
}

extern "C" void kernel_launch(void* const* d_in, const int* in_sizes, int n_in,
                              void* d_out, int out_size, void* d_ws, size_t ws_size,
                              hipStream_t stream)
{
    const int* users = (const int*)d_in[0];
    const int* items = (const int*)d_in[1];
    const int* hop0  = (const int*)d_in[2];
    const int* heads = (const int*)d_in[3];
    const int* rels  = (const int*)d_in[4];
    const int* tails = (const int*)d_in[5];
    const float* entity_emb   = (const float*)d_in[6];
    const float* relation_emb = (const float*)d_in[7];
    const float* rec_user_emb = (const float*)d_in[8];
    const float* rec_item_emb = (const float*)d_in[9];
    const float* W_ih = (const float*)d_in[10];
    const float* W_hh = (const float*)d_in[11];
    const float* b_ih = (const float*)d_in[12];
    const float* b_hh = (const float*)d_in[13];
    float* out = (float*)d_out;

    const int B = in_sizes[0];
    const int blocks = (B + WAVES_PER_BLOCK - 1) / WAVES_PER_BLOCK;
    hipLaunchKernelGGL(ripple_fwd, dim3(blocks), dim3(256), 0, stream,
                       users, items, hop0, heads, rels, tails,
                       entity_emb, relation_emb, rec_user_emb, rec_item_emb,
                       W_ih, W_hh, b_ih, b_hh, out, B);
}

// Round 2
// 48.896 us; speedup vs baseline: 2.3501x; 2.3501x over previous
//
#include <hip/hip_runtime.h>

#define DIM 32
#define KK 64
#define NHOP 2
#define WPB 4                     // waves per block
#define XPAD 80                   // bytes per LDS row (64 data + 16 pad)
#define WLDS (64 * XPAD + 256)    // per-wave LDS: X buffer + q (128B) + bias (128B)

typedef __attribute__((ext_vector_type(8)))  short bf16x8;
typedef __attribute__((ext_vector_type(16))) float f32x16;
typedef __attribute__((ext_vector_type(4)))  unsigned int u32x4;

__device__ __forceinline__ float rcp_fast(float x) { return __builtin_amdgcn_rcpf(x); }

// tanh(x) = 1 - 2/(exp(2x)+1); graceful at +-inf
__device__ __forceinline__ float tanh_fast(float x) {
    float t = __expf(2.0f * x);
    return 1.0f - 2.0f * rcp_fast(t + 1.0f);
}

// pack two f32 -> one dword of 2 bf16 (truncation) via v_perm_b32
__device__ __forceinline__ unsigned pk2(float lo, float hi) {
    return __builtin_amdgcn_perm(__builtin_bit_cast(unsigned, hi),
                                 __builtin_bit_cast(unsigned, lo), 0x07060302u);
}

// read one B-fragment (8 bf16 = 16B) from staged LDS row
__device__ __forceinline__ bf16x8 frag_ld(const unsigned char* Xb, int row, int oct) {
    u32x4 v = *(const u32x4*)(Xb + row * XPAD + oct * 16);
    return __builtin_bit_cast(bf16x8, v);
}

__device__ __forceinline__ void pack_row(const float4* v, u32x4* u) {
    #pragma unroll
    for (int i = 0; i < 4; ++i) {
        u[i][0] = pk2(v[2*i].x,   v[2*i].y);
        u[i][1] = pk2(v[2*i].z,   v[2*i].w);
        u[i][2] = pk2(v[2*i+1].x, v[2*i+1].y);
        u[i][3] = pk2(v[2*i+1].z, v[2*i+1].w);
    }
}

__global__ __launch_bounds__(256) void ripple_mfma(
    const int* __restrict__ users,
    const int* __restrict__ items,
    const int* __restrict__ hop0_items,
    const int* __restrict__ heads,
    const int* __restrict__ relations,
    const int* __restrict__ tails,
    const float* __restrict__ entity_emb,
    const float* __restrict__ relation_emb,
    const float* __restrict__ rec_user_emb,
    const float* __restrict__ rec_item_emb,
    const float* __restrict__ W_ih,
    const float* __restrict__ W_hh,
    const float* __restrict__ b_ih,
    const float* __restrict__ b_hh,
    float* __restrict__ out,
    const int B)
{
    __shared__ __align__(16) unsigned char smem[WPB * WLDS];
    const int wave = threadIdx.x >> 6;
    const int lane = threadIdx.x & 63;
    const int h5   = lane >> 5;     // lane half (k-group)
    const int p    = lane & 31;     // position within half

    unsigned char* Xb = smem + wave * WLDS;
    float* qb = (float*)(Xb + 64 * XPAD);   // 32 f32
    float* bb = qb + 32;                    // 32 f32 (b_ih + b_hh)

    const int b = __builtin_amdgcn_readfirstlane(blockIdx.x * WPB + wave);
    if (b >= B) return;

    const int it = __builtin_amdgcn_readfirstlane(items[b]);
    const int uu = __builtin_amdgcn_readfirstlane(users[b]);

    float tpart = 0.0f;

    // ---- setup: q + bias into LDS, user.q partial ----
    if (lane < DIM) {
        float qd = entity_emb[(size_t)it * DIM + lane] + rec_item_emb[(size_t)it * DIM + lane];
        qb[lane] = qd;
        tpart += rec_user_emb[(size_t)uu * DIM + lane] * qd;
    } else {
        int d = lane - DIM;
        bb[d] = b_ih[d] + b_hh[d];
    }

    // ---- A-operand weight fragments (lane: row = p, k-octet = 16*kt + 8*h5) ----
    bf16x8 wih[4], whh[2];
    {
        const float* wr = W_ih + p * (2 * DIM);
        #pragma unroll
        for (int kt = 0; kt < 4; ++kt) {
            const float* s = wr + kt * 16 + h5 * 8;
            u32x4 u;
            #pragma unroll
            for (int j = 0; j < 4; ++j) u[j] = pk2(s[2*j], s[2*j+1]);
            wih[kt] = __builtin_bit_cast(bf16x8, u);
        }
        const float* wr2 = W_hh + p * DIM;
        #pragma unroll
        for (int kt = 0; kt < 2; ++kt) {
            const float* s = wr2 + kt * 16 + h5 * 8;
            u32x4 u;
            #pragma unroll
            for (int j = 0; j < 4; ++j) u[j] = pk2(s[2*j], s[2*j+1]);
            whh[kt] = __builtin_bit_cast(bf16x8, u);
        }
    }

    // ---- hop-0: sum_k entity[hop0[b,k]] . q ----
    {
        const int idx = hop0_items[b * KK + lane];
        const float4* rp = (const float4*)(entity_emb + (size_t)idx * DIM);
        const float4* qp = (const float4*)qb;
        float part = 0.0f;
        #pragma unroll
        for (int i = 0; i < 8; ++i) {
            float4 v = rp[i]; float4 qv = qp[i];
            part = fmaf(v.x, qv.x, part);
            part = fmaf(v.y, qv.y, part);
            part = fmaf(v.z, qv.z, part);
            part = fmaf(v.w, qv.w, part);
        }
        tpart += part;
    }

    u32x4* Xrow = (u32x4*)(Xb + lane * XPAD);

    #pragma unroll 1
    for (int l = 0; l < NHOP; ++l) {
        const int base = (l * B + b) * KK + lane;
        const int ih  = heads[base];
        const int ir  = relations[base];
        const int itv = tails[base];

        // gather h, t (f32); score = h.t
        float4 hv[8], tv[8];
        {
            const float4* hp = (const float4*)(entity_emb + (size_t)ih  * DIM);
            const float4* tp = (const float4*)(entity_emb + (size_t)itv * DIM);
            #pragma unroll
            for (int i = 0; i < 8; ++i) hv[i] = hp[i];
            #pragma unroll
            for (int i = 0; i < 8; ++i) tv[i] = tp[i];
        }
        float score = 0.0f;
        #pragma unroll
        for (int i = 0; i < 8; ++i) {
            score = fmaf(hv[i].x, tv[i].x, score);
            score = fmaf(hv[i].y, tv[i].y, score);
            score = fmaf(hv[i].z, tv[i].z, score);
            score = fmaf(hv[i].w, tv[i].w, score);
        }
        u32x4 hu[4], tu[4];
        pack_row(hv, hu);
        pack_row(tv, tu);

        // gather r; score += r.r
        u32x4 ru[4];
        {
            float4 rv[8];
            const float4* rp = (const float4*)(relation_emb + (size_t)ir * DIM);
            #pragma unroll
            for (int i = 0; i < 8; ++i) rv[i] = rp[i];
            #pragma unroll
            for (int i = 0; i < 8; ++i) {
                score = fmaf(rv[i].x, rv[i].x, score);
                score = fmaf(rv[i].y, rv[i].y, score);
                score = fmaf(rv[i].z, rv[i].z, score);
                score = fmaf(rv[i].w, rv[i].w, score);
            }
            pack_row(rv, ru);
        }

        // ---- stage r; C_r = bias + W_r . r ----
        #pragma unroll
        for (int i = 0; i < 4; ++i) Xrow[i] = ru[i];

        f32x16 accA[2], accB[2];
        {
            f32x16 bias_v;
            const float4* bp = (const float4*)bb;
            #pragma unroll
            for (int Q = 0; Q < 4; ++Q) {
                float4 bq = bp[2 * Q + h5];   // d-quad base = 8Q + 4*h5
                bias_v[4*Q+0] = bq.x; bias_v[4*Q+1] = bq.y;
                bias_v[4*Q+2] = bq.z; bias_v[4*Q+3] = bq.w;
            }
            accA[0] = bias_v; accA[1] = bias_v;
        }
        #pragma unroll
        for (int nt = 0; nt < 2; ++nt)
            #pragma unroll
            for (int kt = 0; kt < 2; ++kt)
                accA[nt] = __builtin_amdgcn_mfma_f32_32x32x16_bf16(
                    wih[2 + kt], frag_ld(Xb, 32*nt + p, 2*kt + h5), accA[nt], 0, 0, 0);
        accB[0] = accA[0]; accB[1] = accA[1];

        // ---- stage h; SH = C_r + W_h . h  (into accB) ----
        #pragma unroll
        for (int i = 0; i < 4; ++i) Xrow[i] = hu[i];
        #pragma unroll
        for (int nt = 0; nt < 2; ++nt)
            #pragma unroll
            for (int kt = 0; kt < 2; ++kt)
                accB[nt] = __builtin_amdgcn_mfma_f32_32x32x16_bf16(
                    wih[kt], frag_ld(Xb, 32*nt + p, 2*kt + h5), accB[nt], 0, 0, 0);

        // ---- stage t; ST = C_r + W_h . t  (into accA) ----
        #pragma unroll
        for (int i = 0; i < 4; ++i) Xrow[i] = tu[i];
        #pragma unroll
        for (int nt = 0; nt < 2; ++nt)
            #pragma unroll
            for (int kt = 0; kt < 2; ++kt)
                accA[nt] = __builtin_amdgcn_mfma_f32_32x32x16_bf16(
                    wih[kt], frag_ld(Xb, 32*nt + p, 2*kt + h5), accA[nt], 0, 0, 0);

        // ---- h1 = tanh(SH): pack to bf16, write C/D-aligned quads to LDS ----
        #pragma unroll
        for (int nt = 0; nt < 2; ++nt) {
            float t0[16];
            #pragma unroll
            for (int j = 0; j < 16; ++j) t0[j] = tanh_fast(accB[nt][j]);
            unsigned char* hrow = Xb + (32 * nt + p) * XPAD;
            #pragma unroll
            for (int Q = 0; Q < 4; ++Q) {
                uint2 w;
                w.x = pk2(t0[4*Q+0], t0[4*Q+1]);
                w.y = pk2(t0[4*Q+2], t0[4*Q+3]);
                *(uint2*)(hrow + 16 * Q + 8 * h5) = w;   // d-quad = 8Q + 4*h5
            }
        }

        // ---- step2: PRE = ST + W_hh . h1  (into accA) ----
        #pragma unroll
        for (int nt = 0; nt < 2; ++nt)
            #pragma unroll
            for (int kt = 0; kt < 2; ++kt)
                accA[nt] = __builtin_amdgcn_mfma_f32_32x32x16_bf16(
                    whh[kt], frag_ld(Xb, 32*nt + p, 2*kt + h5), accA[nt], 0, 0, 0);

        // ---- h2 = tanh(PRE); s = h2 . q ; softmax-weighted accumulate ----
        float qf[16];
        {
            const float4* qp4 = (const float4*)qb;
            #pragma unroll
            for (int Q = 0; Q < 4; ++Q) {
                float4 v = qp4[2 * Q + h5];
                qf[4*Q+0] = v.x; qf[4*Q+1] = v.y; qf[4*Q+2] = v.z; qf[4*Q+3] = v.w;
            }
        }
        float sd0 = 0.0f, sd1 = 0.0f;
        #pragma unroll
        for (int j = 0; j < 16; ++j) sd0 = fmaf(tanh_fast(accA[0][j]), qf[j], sd0);
        #pragma unroll
        for (int j = 0; j < 16; ++j) sd1 = fmaf(tanh_fast(accA[1][j]), qf[j], sd1);
        sd0 += __shfl_xor(sd0, 32, 64);   // merge complementary d-halves
        sd1 += __shfl_xor(sd1, 32, 64);
        float sown = (lane < 32) ? sd0 : sd1;   // this lane's own triple T = lane

        float ex  = __expf(score);        // scores bounded (~|2|): safe
        float num = ex * sown, den = ex;
        #pragma unroll
        for (int m = 1; m <= 32; m <<= 1) {
            num += __shfl_xor(num, m, 64);
            den += __shfl_xor(den, m, 64);
        }
        tpart += (lane == 0) ? num * rcp_fast(den) : 0.0f;
    }

    // ---- final reduce + sigmoid ----
    #pragma unroll
    for (int m = 1; m <= 32; m <<= 1) tpart += __shfl_xor(tpart, m, 64);
    if (lane == 0) out[b] = rcp_fast(1.0f + __expf(-tpart));
}

extern "C" void kernel_launch(void* const* d_in, const int* in_sizes, int n_in,
                              void* d_out, int out_size, void* d_ws, size_t ws_size,
                              hipStream_t stream)
{
    const int* users = (const int*)d_in[0];
    const int* items = (const int*)d_in[1];
    const int* hop0  = (const int*)d_in[2];
    const int* heads = (const int*)d_in[3];
    const int* rels  = (const int*)d_in[4];
    const int* tails = (const int*)d_in[5];
    const float* entity_emb   = (const float*)d_in[6];
    const float* relation_emb = (const float*)d_in[7];
    const float* rec_user_emb = (const float*)d_in[8];
    const float* rec_item_emb = (const float*)d_in[9];
    const float* W_ih = (const float*)d_in[10];
    const float* W_hh = (const float*)d_in[11];
    const float* b_ih = (const float*)d_in[12];
    const float* b_hh = (const float*)d_in[13];
    float* out = (float*)d_out;

    const int B = in_sizes[0];
    const int blocks = (B + WPB - 1) / WPB;
    hipLaunchKernelGGL(ripple_mfma, dim3(blocks), dim3(256), 0, stream,
                       users, items, hop0, rels ? heads : heads, rels, tails,
                       entity_emb, relation_emb, rec_user_emb, rec_item_emb,
                       W_ih, W_hh, b_ih, b_hh, out, B);
}